// Round 19
// baseline (72.611 us; speedup 1.0000x reference)
//
#include <hip/hip_runtime.h>

namespace {

constexpr int kB = 4;
constexpr int kT = 512;
constexpr int kH = 256;

__device__ __forceinline__ float rcpf(float x) {
  return __builtin_amdgcn_rcpf(x);
}

// ---------------- diagnostic: empty kernel (boundary-cost probe) ------------
__global__ void nop_kernel() {}

// ---------------- k0: transpose W1,W2 (H x H) into Wt ----------------
__global__ __launch_bounds__(256) void transpose_w_kernel(
    const float* __restrict__ W1, const float* __restrict__ W2,
    float* __restrict__ Wt1, float* __restrict__ Wt2) {
  __shared__ float tile[32][33];
  const float* Win = (blockIdx.z == 0) ? W1 : W2;
  float* Wout = (blockIdx.z == 0) ? Wt1 : Wt2;
  const int jo = blockIdx.x * 32, ho = blockIdx.y * 32;
  const int c = threadIdx.x & 31, r0 = threadIdx.x >> 5;
#pragma unroll
  for (int p = 0; p < 4; ++p)
    tile[r0 + 8 * p][c] = Win[(size_t)(ho + r0 + 8 * p) * kH + jo + c];
  __syncthreads();
#pragma unroll
  for (int p = 0; p < 4; ++p)
    Wout[(size_t)(jo + r0 + 8 * p) * kH + ho + c] = tile[c][r0 + 8 * p];
}

// ---------------- k1: projections (r12 BK=16 ring form) ----------------
__global__ __launch_bounds__(256) void proj_kernel(
    const float* __restrict__ X, const float* __restrict__ Wt1,
    const float* __restrict__ Wt2, float* __restrict__ EQt,
    float* __restrict__ EKt) {
  __shared__ __align__(16) float ws4[4][16][kH];  // 64 KB ring

  const int tid = threadIdx.x;  // h
  const int w = tid >> 6, lane = tid & 63;
  const int row0 = blockIdx.x * 8;
  const float* Wt = (blockIdx.y == 0) ? Wt1 : Wt2;
  float* dst = (blockIdx.y == 0) ? EQt : EKt;

  const float* gw = Wt + (size_t)(4 * w) * kH + lane * 4;

#define PSTAGE(buf, c)                                                       \
  {                                                                          \
    const size_t go = (size_t)(c) * 16 * kH;                                 \
    __builtin_amdgcn_global_load_lds(                                        \
        (const __attribute__((address_space(1))) void*)(gw + go),            \
        (__attribute__((address_space(3))) void*)&ws4[buf][4 * w][0], 16, 0, \
        0);                                                                  \
    __builtin_amdgcn_global_load_lds(                                        \
        (const __attribute__((address_space(1))) void*)(gw + go + kH),       \
        (__attribute__((address_space(3))) void*)&ws4[buf][4 * w + 1][0], 16,\
        0, 0);                                                               \
    __builtin_amdgcn_global_load_lds(                                        \
        (const __attribute__((address_space(1))) void*)(gw + go + 2 * kH),   \
        (__attribute__((address_space(3))) void*)&ws4[buf][4 * w + 2][0], 16,\
        0, 0);                                                               \
    __builtin_amdgcn_global_load_lds(                                        \
        (const __attribute__((address_space(1))) void*)(gw + go + 3 * kH),   \
        (__attribute__((address_space(3))) void*)&ws4[buf][4 * w + 3][0], 16,\
        0, 0);                                                               \
  }

  float acc[8];
#pragma unroll
  for (int i = 0; i < 8; ++i) acc[i] = 0.0f;

  PSTAGE(0, 0)
  PSTAGE(1, 1)
  PSTAGE(2, 2)

#pragma unroll 1
  for (int c = 0; c < 16; ++c) {
    if (c <= 13) {
      asm volatile("s_waitcnt vmcnt(8)" ::: "memory");
    } else if (c == 14) {
      asm volatile("s_waitcnt vmcnt(4)" ::: "memory");
    } else {
      asm volatile("s_waitcnt vmcnt(0)" ::: "memory");
    }
    __builtin_amdgcn_s_barrier();
    __builtin_amdgcn_sched_barrier(0);
    if (c <= 12) PSTAGE((c + 3) & 3, c + 3)
    const int bf = c & 3;
#pragma unroll
    for (int u = 0; u < 16; ++u) {
      const float wv = ws4[bf][u][tid];
#pragma unroll
      for (int i = 0; i < 8; ++i)
        acc[i] = __builtin_fmaf(X[(size_t)(row0 + i) * kH + c * 16 + u], wv,
                                acc[i]);
    }
  }
#undef PSTAGE

  const int bb = row0 >> 9, r0 = row0 & (kT - 1);
  float* out = dst + ((size_t)(bb * kH + tid)) * kT + r0;
  float4 lo = {__expf(2.0f * acc[0]), __expf(2.0f * acc[1]),
               __expf(2.0f * acc[2]), __expf(2.0f * acc[3])};
  float4 hi = {__expf(2.0f * acc[4]), __expf(2.0f * acc[5]),
               __expf(2.0f * acc[6]), __expf(2.0f * acc[7])};
  *reinterpret_cast<float4*>(out) = lo;
  *reinterpret_cast<float4*>(out + 4) = hi;
}

// ---------------- k2: causal score kernel, 4-deep LDS ring (r7 form) --------
__global__ __launch_bounds__(256) void score_kernel(
    const float* __restrict__ EQt, const float* __restrict__ EKt,
    const float* __restrict__ v, float* __restrict__ Sc) {
  __shared__ __align__(16) float eqs[4][32 * 32];  // [buf][h*32 + t] 16KB
  __shared__ __align__(16) float eks[4][32 * 32];  // [buf][h*32 + s] 16KB

  const int tid = threadIdx.x;
  const int w = tid >> 6, lane = tid & 63;
  const int blk = blockIdx.x;
  const int xcd = blk & 7;
  const int b = xcd >> 1;  // XCD-pinned batch
  const int tIdx = (xcd & 1) * 68 + (blk >> 3);  // 0..135 causal 32x32 tiles

  int ti = (int)((__builtin_sqrtf(8.0f * (float)tIdx + 1.0f) - 1.0f) * 0.5f);
  while ((ti + 1) * (ti + 2) / 2 <= tIdx) ++ti;
  while (ti * (ti + 1) / 2 > tIdx) --ti;
  const int si = tIdx - ti * (ti + 1) / 2;
  const int t0 = ti * 32, s0 = si * 32;

  const int hoff = w * 8 + (lane >> 3);
  const int coff = (lane & 7) * 4;
  const float* gq = EQt + ((size_t)(b * kH + hoff) * kT) + t0 + coff;
  const float* gk = EKt + ((size_t)(b * kH + hoff) * kT) + s0 + coff;
  float* lqw = &eqs[0][0] + w * 256;  // wave-uniform LDS dest base
  float* lkw = &eks[0][0] + w * 256;

#define STAGE(buf, c)                                                        \
  {                                                                          \
    const size_t go = (size_t)(c) * 32 * kT;                                 \
    __builtin_amdgcn_global_load_lds(                                        \
        (const __attribute__((address_space(1))) void*)(gq + go),            \
        (__attribute__((address_space(3))) void*)(lqw + (buf)*1024), 16, 0,  \
        0);                                                                  \
    __builtin_amdgcn_global_load_lds(                                        \
        (const __attribute__((address_space(1))) void*)(gk + go),            \
        (__attribute__((address_space(3))) void*)(lkw + (buf)*1024), 16, 0,  \
        0);                                                                  \
  }

  const int wt = w >> 1, wsx = w & 1;
  const int tq = wt * 16 + 2 * (lane >> 3);
  const int sk = wsx * 16 + 2 * (lane & 7);

  float ac0 = 0.f, ac1 = 0.f, ac2 = 0.f, ac3 = 0.f;
  float ac4 = 0.f, ac5 = 0.f, ac6 = 0.f, ac7 = 0.f;

  STAGE(0, 0)
  STAGE(1, 1)
  STAGE(2, 2)

#pragma unroll 1
  for (int c = 0; c < 8; ++c) {
    if (c <= 5) {
      asm volatile("s_waitcnt vmcnt(4)" ::: "memory");
    } else if (c == 6) {
      asm volatile("s_waitcnt vmcnt(2)" ::: "memory");
    } else {
      asm volatile("s_waitcnt vmcnt(0)" ::: "memory");
    }
    __builtin_amdgcn_s_barrier();
    __builtin_amdgcn_sched_barrier(0);
    if (c <= 4) STAGE((c + 3) & 3, c + 3)
    const int boff = (c & 3) * 1024;
    const float* vp = v + c * 32;  // uniform -> s_load
#pragma unroll
    for (int h = 0; h < 32; h += 2) {
      const float2 qA = *reinterpret_cast<const float2*>(&eqs[0][boff + h * 32 + tq]);
      const float2 kA = *reinterpret_cast<const float2*>(&eks[0][boff + h * 32 + sk]);
      const float2 qB = *reinterpret_cast<const float2*>(&eqs[0][boff + h * 32 + 32 + tq]);
      const float2 kB = *reinterpret_cast<const float2*>(&eks[0][boff + h * 32 + 32 + sk]);
      const float vA = vp[h], vB = vp[h + 1];
      ac0 = __builtin_fmaf(vA, rcpf(__builtin_fmaf(qA.x, kA.x, 1.0f)), ac0);
      ac1 = __builtin_fmaf(vA, rcpf(__builtin_fmaf(qA.x, kA.y, 1.0f)), ac1);
      ac2 = __builtin_fmaf(vA, rcpf(__builtin_fmaf(qA.y, kA.x, 1.0f)), ac2);
      ac3 = __builtin_fmaf(vA, rcpf(__builtin_fmaf(qA.y, kA.y, 1.0f)), ac3);
      ac4 = __builtin_fmaf(vB, rcpf(__builtin_fmaf(qB.x, kB.x, 1.0f)), ac4);
      ac5 = __builtin_fmaf(vB, rcpf(__builtin_fmaf(qB.x, kB.y, 1.0f)), ac5);
      ac6 = __builtin_fmaf(vB, rcpf(__builtin_fmaf(qB.y, kB.x, 1.0f)), ac6);
      ac7 = __builtin_fmaf(vB, rcpf(__builtin_fmaf(qB.y, kB.y, 1.0f)), ac7);
    }
  }
#undef STAGE

  float vv = v[lane] + v[lane + 64] + v[lane + 128] + v[lane + 192];
#pragma unroll
  for (int off = 32; off > 0; off >>= 1) vv += __shfl_xor(vv, off, 64);

  float2 row0v = {__builtin_fmaf(-2.0f, ac0 + ac4, vv),
                  __builtin_fmaf(-2.0f, ac1 + ac5, vv)};
  float2 row1v = {__builtin_fmaf(-2.0f, ac2 + ac6, vv),
                  __builtin_fmaf(-2.0f, ac3 + ac7, vv)};
  float* so = Sc + ((size_t)(b * kT + t0 + tq)) * kT + s0 + sk;
  *reinterpret_cast<float2*>(so) = row0v;
  *reinterpret_cast<float2*>(so + kT) = row1v;
}

// ---------------- k3: softmax + weights + context (8 rows/block, r10 form) --
__global__ __launch_bounds__(512) void attn2_kernel(
    const float* __restrict__ X, float* wsc, float* __restrict__ ctx) {
  __shared__ float wls[8][kT + 8];   // weights; row stride 2080B (16B-aligned)
  __shared__ float pc[2][8][kH];     // partial context [half][r][h]

  const int id = blockIdx.x;
  const int xcd = id & 7;
  const int b = xcd >> 1;                      // XCD-pinned batch
  const int sub = (xcd & 1) * 32 + (id >> 3);  // 0..63
  const int row0 = sub * 8;
  const int tid = threadIdx.x;
  const int w = tid >> 6, lane = tid & 63;

  // ---- softmax: wave w -> row t = row0 + w ----
  const int t = row0 + w;
  float* srow = wsc + ((size_t)(b * kT + t)) * kT;
  const int sbase8 = lane * 8;
  float4 s4a = *reinterpret_cast<const float4*>(srow + sbase8);
  float4 s4b = *reinterpret_cast<const float4*>(srow + sbase8 + 4);
  float p[8];
  p[0] = (sbase8 + 0 <= t) ? __expf(s4a.x) : 0.f;
  p[1] = (sbase8 + 1 <= t) ? __expf(s4a.y) : 0.f;
  p[2] = (sbase8 + 2 <= t) ? __expf(s4a.z) : 0.f;
  p[3] = (sbase8 + 3 <= t) ? __expf(s4a.w) : 0.f;
  p[4] = (sbase8 + 4 <= t) ? __expf(s4b.x) : 0.f;
  p[5] = (sbase8 + 5 <= t) ? __expf(s4b.y) : 0.f;
  p[6] = (sbase8 + 6 <= t) ? __expf(s4b.z) : 0.f;
  p[7] = (sbase8 + 7 <= t) ? __expf(s4b.w) : 0.f;
  float l = ((p[0] + p[1]) + (p[2] + p[3])) + ((p[4] + p[5]) + (p[6] + p[7]));
#pragma unroll
  for (int off = 32; off > 0; off >>= 1) l += __shfl_xor(l, off, 64);
  const float rs = rcpf(l);
#pragma unroll
  for (int j = 0; j < 8; ++j) p[j] *= rs;
  float4 o4a = {p[0], p[1], p[2], p[3]};
  float4 o4b = {p[4], p[5], p[6], p[7]};
  *reinterpret_cast<float4*>(srow + sbase8) = o4a;
  *reinterpret_cast<float4*>(srow + sbase8 + 4) = o4b;
#pragma unroll
  for (int j = 0; j < 8; ++j) wls[w][sbase8 + j] = p[j];
  __syncthreads();

  // ---- context ----
  const int h = tid & (kH - 1);
  const int half = tid >> 8;
  const float* Xb = X + ((size_t)b * kT) * kH + h;
  float acc[8];
#pragma unroll
  for (int r = 0; r < 8; ++r) acc[r] = 0.f;
  const int sb = half * 256;
#pragma unroll 2
  for (int so = 0; so < 256; so += 4) {
    const int s = sb + so;
    const float x0 = Xb[(size_t)(s + 0) * kH];
    const float x1 = Xb[(size_t)(s + 1) * kH];
    const float x2 = Xb[(size_t)(s + 2) * kH];
    const float x3 = Xb[(size_t)(s + 3) * kH];
#pragma unroll
    for (int r = 0; r < 8; ++r) {
      const float4 wr = *reinterpret_cast<const float4*>(&wls[r][s]);
      float a = __builtin_fmaf(wr.x, x0, acc[r]);
      a = __builtin_fmaf(wr.y, x1, a);
      a = __builtin_fmaf(wr.z, x2, a);
      acc[r] = __builtin_fmaf(wr.w, x3, a);
    }
  }
#pragma unroll
  for (int r = 0; r < 8; ++r) pc[half][r][h] = acc[r];
  __syncthreads();

#pragma unroll
  for (int q = 0; q < 4; ++q) {
    const int idx = q * 512 + tid;       // 0..2047
    const int r = idx >> 8, hh = idx & (kH - 1);
    ctx[((size_t)(b * kT + row0 + r)) * kH + hh] = pc[0][r][hh] + pc[1][r][hh];
  }
}

}  // namespace

extern "C" void kernel_launch(void* const* d_in, const int* in_sizes, int n_in,
                              void* d_out, int out_size, void* d_ws,
                              size_t ws_size, hipStream_t stream) {
  const float* X = (const float*)d_in[0];
  const float* W1 = (const float*)d_in[1];
  const float* W2 = (const float*)d_in[2];
  const float* v = (const float*)d_in[3];

  float* ctx = (float*)d_out;                   // [B*T][H]  2 MB
  float* wout = ctx + (size_t)kB * kT * kH;     // [B*T][T]  4 MB
  float* Wt1 = wout;                            // 256 KB  (k0 -> k1)
  float* Wt2 = wout + (size_t)kH * kH;          // 256 KB  (k0 -> k1)
  float* Sc = wout;                             // 4 MB    (k2 -> k3)
  float* EQt = (float*)d_ws;                    // [B][H][T]  2 MB
  float* EKt = EQt + (size_t)kB * kH * kT;      // [B][H][T]  2 MB

  // DIAGNOSTIC (this round only): 4 empty kernels inserted between the real
  // dispatches. dtotal vs r12 (66.4) = 4 x per-boundary overhead.
  transpose_w_kernel<<<dim3(8, 8, 2), 256, 0, stream>>>(W1, W2, Wt1, Wt2);
  nop_kernel<<<1, 64, 0, stream>>>();
  proj_kernel<<<dim3(kB * kT / 8, 2), 256, 0, stream>>>(X, Wt1, Wt2, EQt, EKt);
  nop_kernel<<<1, 64, 0, stream>>>();
  score_kernel<<<544, 256, 0, stream>>>(EQt, EKt, v, Sc);
  nop_kernel<<<1, 64, 0, stream>>>();
  attn2_kernel<<<256, 512, 0, stream>>>(X, Sc, ctx);
  nop_kernel<<<1, 64, 0, stream>>>();
}

// Round 20
// 60.540 us; speedup vs baseline: 1.1994x; 1.1994x over previous
//
#include <hip/hip_runtime.h>

namespace {

constexpr int kB = 4;
constexpr int kT = 512;
constexpr int kH = 256;

__device__ __forceinline__ float rcpf(float x) {
  return __builtin_amdgcn_rcpf(x);
}

// ---------------- k0: transpose W1,W2 (H x H) into Wt ----------------
__global__ __launch_bounds__(256) void transpose_w_kernel(
    const float* __restrict__ W1, const float* __restrict__ W2,
    float* __restrict__ Wt1, float* __restrict__ Wt2) {
  __shared__ float tile[32][33];
  const float* Win = (blockIdx.z == 0) ? W1 : W2;
  float* Wout = (blockIdx.z == 0) ? Wt1 : Wt2;
  const int jo = blockIdx.x * 32, ho = blockIdx.y * 32;
  const int c = threadIdx.x & 31, r0 = threadIdx.x >> 5;
#pragma unroll
  for (int p = 0; p < 4; ++p)
    tile[r0 + 8 * p][c] = Win[(size_t)(ho + r0 + 8 * p) * kH + jo + c];
  __syncthreads();
#pragma unroll
  for (int p = 0; p < 4; ++p)
    Wout[(size_t)(jo + r0 + 8 * p) * kH + ho + c] = tile[c][r0 + 8 * p];
}

// ---------------- k1: projections (r12 BK=16 ring form) ----------------
__global__ __launch_bounds__(256) void proj_kernel(
    const float* __restrict__ X, const float* __restrict__ Wt1,
    const float* __restrict__ Wt2, float* __restrict__ EQt,
    float* __restrict__ EKt) {
  __shared__ __align__(16) float ws4[4][16][kH];  // 64 KB ring

  const int tid = threadIdx.x;  // h
  const int w = tid >> 6, lane = tid & 63;
  const int row0 = blockIdx.x * 8;
  const float* Wt = (blockIdx.y == 0) ? Wt1 : Wt2;
  float* dst = (blockIdx.y == 0) ? EQt : EKt;

  const float* gw = Wt + (size_t)(4 * w) * kH + lane * 4;

#define PSTAGE(buf, c)                                                       \
  {                                                                          \
    const size_t go = (size_t)(c) * 16 * kH;                                 \
    __builtin_amdgcn_global_load_lds(                                        \
        (const __attribute__((address_space(1))) void*)(gw + go),            \
        (__attribute__((address_space(3))) void*)&ws4[buf][4 * w][0], 16, 0, \
        0);                                                                  \
    __builtin_amdgcn_global_load_lds(                                        \
        (const __attribute__((address_space(1))) void*)(gw + go + kH),       \
        (__attribute__((address_space(3))) void*)&ws4[buf][4 * w + 1][0], 16,\
        0, 0);                                                               \
    __builtin_amdgcn_global_load_lds(                                        \
        (const __attribute__((address_space(1))) void*)(gw + go + 2 * kH),   \
        (__attribute__((address_space(3))) void*)&ws4[buf][4 * w + 2][0], 16,\
        0, 0);                                                               \
    __builtin_amdgcn_global_load_lds(                                        \
        (const __attribute__((address_space(1))) void*)(gw + go + 3 * kH),   \
        (__attribute__((address_space(3))) void*)&ws4[buf][4 * w + 3][0], 16,\
        0, 0);                                                               \
  }

  float acc[8];
#pragma unroll
  for (int i = 0; i < 8; ++i) acc[i] = 0.0f;

  PSTAGE(0, 0)
  PSTAGE(1, 1)
  PSTAGE(2, 2)

#pragma unroll 1
  for (int c = 0; c < 16; ++c) {
    if (c <= 13) {
      asm volatile("s_waitcnt vmcnt(8)" ::: "memory");
    } else if (c == 14) {
      asm volatile("s_waitcnt vmcnt(4)" ::: "memory");
    } else {
      asm volatile("s_waitcnt vmcnt(0)" ::: "memory");
    }
    __builtin_amdgcn_s_barrier();
    __builtin_amdgcn_sched_barrier(0);
    if (c <= 12) PSTAGE((c + 3) & 3, c + 3)
    const int bf = c & 3;
#pragma unroll
    for (int u = 0; u < 16; ++u) {
      const float wv = ws4[bf][u][tid];
#pragma unroll
      for (int i = 0; i < 8; ++i)
        acc[i] = __builtin_fmaf(X[(size_t)(row0 + i) * kH + c * 16 + u], wv,
                                acc[i]);
    }
  }
#undef PSTAGE

  const int bb = row0 >> 9, r0 = row0 & (kT - 1);
  float* out = dst + ((size_t)(bb * kH + tid)) * kT + r0;
  float4 lo = {__expf(2.0f * acc[0]), __expf(2.0f * acc[1]),
               __expf(2.0f * acc[2]), __expf(2.0f * acc[3])};
  float4 hi = {__expf(2.0f * acc[4]), __expf(2.0f * acc[5]),
               __expf(2.0f * acc[6]), __expf(2.0f * acc[7])};
  *reinterpret_cast<float4*>(out) = lo;
  *reinterpret_cast<float4*>(out + 4) = hi;
}

// ---------------- k2: causal score kernel, pairwise-rcp inner loop ----------
// CHANGE: vA/dA + vB/dB = (vA*dB + vB*dA) * rcp(dA*dB) merges the h/h+1
// rcp pair -> half the trans-pipe ops, fewer issue slots. Exact math.
__global__ __launch_bounds__(256) void score_kernel(
    const float* __restrict__ EQt, const float* __restrict__ EKt,
    const float* __restrict__ v, float* __restrict__ Sc) {
  __shared__ __align__(16) float eqs[4][32 * 32];  // [buf][h*32 + t] 16KB
  __shared__ __align__(16) float eks[4][32 * 32];  // [buf][h*32 + s] 16KB

  const int tid = threadIdx.x;
  const int w = tid >> 6, lane = tid & 63;
  const int blk = blockIdx.x;
  const int xcd = blk & 7;
  const int b = xcd >> 1;  // XCD-pinned batch
  const int tIdx = (xcd & 1) * 68 + (blk >> 3);  // 0..135 causal 32x32 tiles

  int ti = (int)((__builtin_sqrtf(8.0f * (float)tIdx + 1.0f) - 1.0f) * 0.5f);
  while ((ti + 1) * (ti + 2) / 2 <= tIdx) ++ti;
  while (ti * (ti + 1) / 2 > tIdx) --ti;
  const int si = tIdx - ti * (ti + 1) / 2;
  const int t0 = ti * 32, s0 = si * 32;

  const int hoff = w * 8 + (lane >> 3);
  const int coff = (lane & 7) * 4;
  const float* gq = EQt + ((size_t)(b * kH + hoff) * kT) + t0 + coff;
  const float* gk = EKt + ((size_t)(b * kH + hoff) * kT) + s0 + coff;
  float* lqw = &eqs[0][0] + w * 256;  // wave-uniform LDS dest base
  float* lkw = &eks[0][0] + w * 256;

#define STAGE(buf, c)                                                        \
  {                                                                          \
    const size_t go = (size_t)(c) * 32 * kT;                                 \
    __builtin_amdgcn_global_load_lds(                                        \
        (const __attribute__((address_space(1))) void*)(gq + go),            \
        (__attribute__((address_space(3))) void*)(lqw + (buf)*1024), 16, 0,  \
        0);                                                                  \
    __builtin_amdgcn_global_load_lds(                                        \
        (const __attribute__((address_space(1))) void*)(gk + go),            \
        (__attribute__((address_space(3))) void*)(lkw + (buf)*1024), 16, 0,  \
        0);                                                                  \
  }

  const int wt = w >> 1, wsx = w & 1;
  const int tq = wt * 16 + 2 * (lane >> 3);
  const int sk = wsx * 16 + 2 * (lane & 7);

  float ac0 = 0.f, ac1 = 0.f, ac2 = 0.f, ac3 = 0.f;

  STAGE(0, 0)
  STAGE(1, 1)
  STAGE(2, 2)

#pragma unroll 1
  for (int c = 0; c < 8; ++c) {
    if (c <= 5) {
      asm volatile("s_waitcnt vmcnt(4)" ::: "memory");
    } else if (c == 6) {
      asm volatile("s_waitcnt vmcnt(2)" ::: "memory");
    } else {
      asm volatile("s_waitcnt vmcnt(0)" ::: "memory");
    }
    __builtin_amdgcn_s_barrier();
    __builtin_amdgcn_sched_barrier(0);
    if (c <= 4) STAGE((c + 3) & 3, c + 3)
    const int boff = (c & 3) * 1024;
    const float* vp = v + c * 32;  // uniform -> s_load
#pragma unroll
    for (int h = 0; h < 32; h += 2) {
      const float2 qA = *reinterpret_cast<const float2*>(&eqs[0][boff + h * 32 + tq]);
      const float2 kA = *reinterpret_cast<const float2*>(&eks[0][boff + h * 32 + sk]);
      const float2 qB = *reinterpret_cast<const float2*>(&eqs[0][boff + h * 32 + 32 + tq]);
      const float2 kB = *reinterpret_cast<const float2*>(&eks[0][boff + h * 32 + 32 + sk]);
      const float vA = vp[h], vB = vp[h + 1];
      {
        const float dA = __builtin_fmaf(qA.x, kA.x, 1.0f);
        const float dB = __builtin_fmaf(qB.x, kB.x, 1.0f);
        const float nm = __builtin_fmaf(vB, dA, vA * dB);
        ac0 = __builtin_fmaf(nm, rcpf(dA * dB), ac0);
      }
      {
        const float dA = __builtin_fmaf(qA.x, kA.y, 1.0f);
        const float dB = __builtin_fmaf(qB.x, kB.y, 1.0f);
        const float nm = __builtin_fmaf(vB, dA, vA * dB);
        ac1 = __builtin_fmaf(nm, rcpf(dA * dB), ac1);
      }
      {
        const float dA = __builtin_fmaf(qA.y, kA.x, 1.0f);
        const float dB = __builtin_fmaf(qB.y, kB.x, 1.0f);
        const float nm = __builtin_fmaf(vB, dA, vA * dB);
        ac2 = __builtin_fmaf(nm, rcpf(dA * dB), ac2);
      }
      {
        const float dA = __builtin_fmaf(qA.y, kA.y, 1.0f);
        const float dB = __builtin_fmaf(qB.y, kB.y, 1.0f);
        const float nm = __builtin_fmaf(vB, dA, vA * dB);
        ac3 = __builtin_fmaf(nm, rcpf(dA * dB), ac3);
      }
    }
  }
#undef STAGE

  float vv = v[lane] + v[lane + 64] + v[lane + 128] + v[lane + 192];
#pragma unroll
  for (int off = 32; off > 0; off >>= 1) vv += __shfl_xor(vv, off, 64);

  float2 row0v = {__builtin_fmaf(-2.0f, ac0, vv),
                  __builtin_fmaf(-2.0f, ac1, vv)};
  float2 row1v = {__builtin_fmaf(-2.0f, ac2, vv),
                  __builtin_fmaf(-2.0f, ac3, vv)};
  float* so = Sc + ((size_t)(b * kT + t0 + tq)) * kT + s0 + sk;
  *reinterpret_cast<float2*>(so) = row0v;
  *reinterpret_cast<float2*>(so + kT) = row1v;
}

// ---------------- k3: softmax + weights + context, lane-private h -----------
// CHANGE: context phase gives each LANE 4 consecutive h (h = 4*lane..+3), so
// the h-dimension spans ONE wave and each weight float4 is read from LDS
// once per s-chunk (wave) instead of once per each of 4 h-spanning waves:
// LDS-pipe cost /4 (it's CU-shared -> was the TLP-invariant 20us pin).
// Wave w owns s-chunk [64w, 64w+64); partials combined via pc[8][8][256].
__global__ __launch_bounds__(512) void attn2_kernel(
    const float* __restrict__ X, float* wsc, float* __restrict__ ctx) {
  __shared__ float wls[8][kT + 8];              // 16.6KB, rows 16B-aligned
  __shared__ __align__(16) float pc[8][8][kH];  // [s-chunk][r][h] 64KB

  const int id = blockIdx.x;
  const int xcd = id & 7;
  const int b = xcd >> 1;                      // XCD-pinned batch
  const int sub = (xcd & 1) * 32 + (id >> 3);  // 0..63
  const int row0 = sub * 8;
  const int tid = threadIdx.x;
  const int w = tid >> 6, lane = tid & 63;

  // ---- softmax: wave w -> row t = row0 + w ----
  const int t = row0 + w;
  float* srow = wsc + ((size_t)(b * kT + t)) * kT;
  const int sbase8 = lane * 8;
  float4 s4a = *reinterpret_cast<const float4*>(srow + sbase8);
  float4 s4b = *reinterpret_cast<const float4*>(srow + sbase8 + 4);
  float p[8];
  p[0] = (sbase8 + 0 <= t) ? __expf(s4a.x) : 0.f;
  p[1] = (sbase8 + 1 <= t) ? __expf(s4a.y) : 0.f;
  p[2] = (sbase8 + 2 <= t) ? __expf(s4a.z) : 0.f;
  p[3] = (sbase8 + 3 <= t) ? __expf(s4a.w) : 0.f;
  p[4] = (sbase8 + 4 <= t) ? __expf(s4b.x) : 0.f;
  p[5] = (sbase8 + 5 <= t) ? __expf(s4b.y) : 0.f;
  p[6] = (sbase8 + 6 <= t) ? __expf(s4b.z) : 0.f;
  p[7] = (sbase8 + 7 <= t) ? __expf(s4b.w) : 0.f;
  float l = ((p[0] + p[1]) + (p[2] + p[3])) + ((p[4] + p[5]) + (p[6] + p[7]));
#pragma unroll
  for (int off = 32; off > 0; off >>= 1) l += __shfl_xor(l, off, 64);
  const float rs = rcpf(l);
#pragma unroll
  for (int j = 0; j < 8; ++j) p[j] *= rs;
  float4 o4a = {p[0], p[1], p[2], p[3]};
  float4 o4b = {p[4], p[5], p[6], p[7]};
  *reinterpret_cast<float4*>(srow + sbase8) = o4a;
  *reinterpret_cast<float4*>(srow + sbase8 + 4) = o4b;
#pragma unroll
  for (int j = 0; j < 8; ++j) wls[w][sbase8 + j] = p[j];
  __syncthreads();

  // ---- context: wave w -> s in [64w, 64w+64); lane -> h = 4*lane..4*lane+3
  const int h4 = lane * 4;
  const float* Xb = X + ((size_t)b * kT) * kH + h4;
  float4 acc4[8];
#pragma unroll
  for (int r = 0; r < 8; ++r) acc4[r] = {0.f, 0.f, 0.f, 0.f};

#pragma unroll 2
  for (int so = 0; so < 64; so += 4) {
    const int s = (w << 6) + so;
    const float4 x0 = *reinterpret_cast<const float4*>(Xb + (size_t)(s + 0) * kH);
    const float4 x1 = *reinterpret_cast<const float4*>(Xb + (size_t)(s + 1) * kH);
    const float4 x2 = *reinterpret_cast<const float4*>(Xb + (size_t)(s + 2) * kH);
    const float4 x3 = *reinterpret_cast<const float4*>(Xb + (size_t)(s + 3) * kH);
#pragma unroll
    for (int r = 0; r < 8; ++r) {
      const float4 wr = *reinterpret_cast<const float4*>(&wls[r][s]);
      float4 a = acc4[r];
      a.x = __builtin_fmaf(wr.x, x0.x, a.x);
      a.y = __builtin_fmaf(wr.x, x0.y, a.y);
      a.z = __builtin_fmaf(wr.x, x0.z, a.z);
      a.w = __builtin_fmaf(wr.x, x0.w, a.w);
      a.x = __builtin_fmaf(wr.y, x1.x, a.x);
      a.y = __builtin_fmaf(wr.y, x1.y, a.y);
      a.z = __builtin_fmaf(wr.y, x1.z, a.z);
      a.w = __builtin_fmaf(wr.y, x1.w, a.w);
      a.x = __builtin_fmaf(wr.z, x2.x, a.x);
      a.y = __builtin_fmaf(wr.z, x2.y, a.y);
      a.z = __builtin_fmaf(wr.z, x2.z, a.z);
      a.w = __builtin_fmaf(wr.z, x2.w, a.w);
      a.x = __builtin_fmaf(wr.w, x3.x, a.x);
      a.y = __builtin_fmaf(wr.w, x3.y, a.y);
      a.z = __builtin_fmaf(wr.w, x3.z, a.z);
      a.w = __builtin_fmaf(wr.w, x3.w, a.w);
      acc4[r] = a;
    }
  }
#pragma unroll
  for (int r = 0; r < 8; ++r)
    *reinterpret_cast<float4*>(&pc[w][r][h4]) = acc4[r];
  __syncthreads();

  // ---- combine: wave w -> output row r = w; lane -> 4 consecutive h ----
  float4 sum = {0.f, 0.f, 0.f, 0.f};
#pragma unroll
  for (int c = 0; c < 8; ++c) {
    const float4 q = *reinterpret_cast<const float4*>(&pc[c][w][h4]);
    sum.x += q.x;
    sum.y += q.y;
    sum.z += q.z;
    sum.w += q.w;
  }
  *reinterpret_cast<float4*>(
      ctx + ((size_t)(b * kT + row0 + w)) * kH + h4) = sum;
}

}  // namespace

extern "C" void kernel_launch(void* const* d_in, const int* in_sizes, int n_in,
                              void* d_out, int out_size, void* d_ws,
                              size_t ws_size, hipStream_t stream) {
  const float* X = (const float*)d_in[0];
  const float* W1 = (const float*)d_in[1];
  const float* W2 = (const float*)d_in[2];
  const float* v = (const float*)d_in[3];

  float* ctx = (float*)d_out;                   // [B*T][H]  2 MB
  float* wout = ctx + (size_t)kB * kT * kH;     // [B*T][T]  4 MB
  float* Wt1 = wout;                            // 256 KB  (k0 -> k1)
  float* Wt2 = wout + (size_t)kH * kH;          // 256 KB  (k0 -> k1)
  float* Sc = wout;                             // 4 MB    (k2 -> k3)
  float* EQt = (float*)d_ws;                    // [B][H][T]  2 MB
  float* EKt = EQt + (size_t)kB * kH * kT;      // [B][H][T]  2 MB

  transpose_w_kernel<<<dim3(8, 8, 2), 256, 0, stream>>>(W1, W2, Wt1, Wt2);
  proj_kernel<<<dim3(kB * kT / 8, 2), 256, 0, stream>>>(X, Wt1, Wt2, EQt, EKt);
  score_kernel<<<544, 256, 0, stream>>>(EQt, EKt, v, Sc);
  attn2_kernel<<<256, 512, 0, stream>>>(X, Sc, ctx);
}